// Round 1
// baseline (360.060 us; speedup 1.0000x reference)
//
#include <hip/hip_runtime.h>

// Problem constants
#define HW 64          // H = W = 64
#define NB 16          // batch
#define NC 16          // channels in/out
#define KTOT 784       // 16 * 49 reduction length per output
#define WPB 12544      // KTOT * 16 floats of weights per (i,j)
#define CHUNK_K 128    // k per staged chunk (2048 floats = 8 KB)
#define CHUNK_F 2048

__device__ __forceinline__ int reflect64(int v) {
    if (v < 0) v = -v;
    if (v > 63) v = 126 - v;
    return v;
}

// ---------------------------------------------------------------------------
// Kernel 1: transpose spikes [b][c][h][w] -> sT [c][h][w][b]  (b innermost)
// Writes coalesced (tid == output index); reads are L2-hot (4 MB input).
// ---------------------------------------------------------------------------
__global__ __launch_bounds__(256) void k_transpose(const float* __restrict__ in,
                                                   float* __restrict__ sT) {
    int gid = blockIdx.x * 256 + threadIdx.x;        // 0 .. 1M-1
    int b = gid & 15;
    int w = (gid >> 4) & 63;
    int h = (gid >> 10) & 63;
    int c = (gid >> 16) & 15;
    sT[gid] = in[b * 65536 + c * 4096 + h * 64 + w];
}

// ---------------------------------------------------------------------------
// Kernel 2: locally-connected reduce. One block per (i,j).
// out_compact[ij][bm] = sum_k  sT[c][r(x)][col(y)][b] * W[ij][k][m]
// thread = (kp = wave, m = (lane>>2), bq = lane&3); acc over 4 b's.
// ---------------------------------------------------------------------------
__global__ __launch_bounds__(256) void k_lc(const float* __restrict__ weights,
                                            const float* __restrict__ sT,
                                            float* __restrict__ oc) {
    __shared__ float buf[2][CHUNK_F];                 // 16 KB W double-buffer
    __shared__ __align__(16) unsigned table[KTOT];    // per-block byte offsets into sT

    const int tid = threadIdx.x;
    const int bid = blockIdx.x;
    const int i = bid >> 6;
    const int j = bid & 63;

    // ---- build reflection/offset table (once per block) ----
    if (tid < 196) {
#pragma unroll
        for (int e = 0; e < 4; ++e) {
            int k = tid * 4 + e;
            int c = (k * 1338) >> 16;      // k / 49  (exact for k < 784)
            int xy = k - c * 49;
            int x = (xy * 37) >> 8;        // xy / 7  (exact for xy < 49)
            int y = xy - x * 7;
            int r = reflect64(i + x - 3);
            int col = reflect64(j + y - 3);
            // sT byte offset of (c, r, col, b=0): ((c*4096 + r*64 + col) * 16 floats) * 4 B
            table[k] = (unsigned)(((c << 12) | (r << 6) | col) << 6);
        }
    }

    const int kp = tid >> 6;       // wave id: k-quarter
    const int lane = tid & 63;
    const int m = lane >> 2;       // output channel
    const int bq = lane & 3;       // batch quad
    const char* sTb = (const char*)sT + bq * 16;   // + b-quad within the 64B line

    const float* Wg = weights + (size_t)bid * WPB;
    const float4* Wg4 = (const float4*)Wg;

    float4 acc = make_float4(0.f, 0.f, 0.f, 0.f);

    // prefetch chunk 0 into registers
    float4 s0 = Wg4[tid];
    float4 s1 = Wg4[tid + 256];
    float tailv = 0.f;

    for (int n = 0; n < 6; ++n) {
        __syncthreads();                              // buf[n&1] free (prev compute done)
        float4* bf4 = (float4*)(&buf[n & 1][0]);
        bf4[tid] = s0;
        bf4[tid + 256] = s1;
        if (n < 5) {                                  // prefetch next chunk
            s0 = Wg4[(n + 1) * 512 + tid];
            s1 = Wg4[(n + 1) * 512 + 256 + tid];
        } else {
            tailv = Wg[12288 + tid];                  // tail 16 k = 256 floats
        }
        __syncthreads();                              // publish buf[n&1]

        const float* wb = &buf[n & 1][0];
        const int kb = n * CHUNK_K + kp * 32;         // global k base (table index)
        const int kl = kp * 32;                       // local k within chunk
#pragma unroll
        for (int g = 0; g < 8; ++g) {
            uint4 offs = *(const uint4*)&table[kb + g * 4];
            unsigned oarr[4] = {offs.x, offs.y, offs.z, offs.w};
#pragma unroll
            for (int q = 0; q < 4; ++q) {
                float4 s4 = *(const float4*)(sTb + oarr[q]);
                float w = wb[(kl + g * 4 + q) * 16 + m];
                acc.x += s4.x * w;
                acc.y += s4.y * w;
                acc.z += s4.z * w;
                acc.w += s4.w * w;
            }
        }
    }

    // ---- tail chunk: k = 768..783 (16 k = 256 floats) in buf[0] ----
    __syncthreads();
    buf[0][tid] = tailv;
    __syncthreads();
    {
        const float* wb = &buf[0][0];
        const int kb = 768 + kp * 4;
        const int kl = kp * 4;
        uint4 offs = *(const uint4*)&table[kb];
        unsigned oarr[4] = {offs.x, offs.y, offs.z, offs.w};
#pragma unroll
        for (int q = 0; q < 4; ++q) {
            float4 s4 = *(const float4*)(sTb + oarr[q]);
            float w = wb[(kl + q) * 16 + m];
            acc.x += s4.x * w;
            acc.y += s4.y * w;
            acc.z += s4.z * w;
            acc.w += s4.w * w;
        }
    }

    // ---- reduce the 4 k-quarters (kp) across waves via LDS ----
    __syncthreads();                                  // done reading buf[0]
    float4* scr = (float4*)&buf[0][0];                // reuse as 4 KB scratch
    scr[kp * 64 + lane] = acc;
    __syncthreads();

    // thread t produces bm = t  (b = t>>4, m = t&15)
    const int b = tid >> 4;
    const int mm = tid & 15;
    const int lane_src = mm * 4 + (b >> 2);
    const int d = b & 3;
    float sum = 0.f;
#pragma unroll
    for (int p = 0; p < 4; ++p) {
        float4 v = scr[p * 64 + lane_src];
        float vd = (d == 0) ? v.x : (d == 1) ? v.y : (d == 2) ? v.z : v.w;
        sum += vd;
    }
    oc[(size_t)bid * 256 + tid] = sum;                // coalesced 1 KB per block
}

// ---------------------------------------------------------------------------
// Kernel 3: LDS-tiled transpose oc[ij][bm] -> out[bm][ij], fused LIF update.
// 256 blocks (64 ij-tiles x 4 bm-tiles), 256 threads.
// ---------------------------------------------------------------------------
__global__ __launch_bounds__(256) void k_lif(const float* __restrict__ oc,
                                             const float* __restrict__ membrane,
                                             float* __restrict__ out) {
    __shared__ float tile[64][65];
    const int tb = blockIdx.x;
    const int ij0 = (tb >> 2) * 64;
    const int bm0 = (tb & 3) * 64;
    const int t = threadIdx.x;
    const int r0 = t >> 6;    // 0..3
    const int cl = t & 63;

#pragma unroll
    for (int p = 0; p < 16; ++p) {
        int ijl = p * 4 + r0;
        tile[ijl][cl] = oc[(size_t)(ij0 + ijl) * 256 + bm0 + cl];  // coalesced over bm
    }
    __syncthreads();
#pragma unroll
    for (int p = 0; p < 16; ++p) {
        int bml = p * 4 + r0;
        int ijl = cl;
        float local = tile[ijl][bml];
        size_t idx = (size_t)(bm0 + bml) * 4096 + (ij0 + ijl);     // coalesced over ij
        float memv = membrane[idx] * 0.99f + local;
        float spk = (memv > 1.0f) ? 1.0f : 0.0f;
        float mo = (memv > 1.0f) ? 1.0f : memv;
        out[idx] = spk;                     // spike output
        out[idx + 1048576] = mo;            // membrane output
    }
}

// ---------------------------------------------------------------------------
extern "C" void kernel_launch(void* const* d_in, const int* in_sizes, int n_in,
                              void* d_out, int out_size, void* d_ws, size_t ws_size,
                              hipStream_t stream) {
    const float* spikes = (const float*)d_in[0];     // (16,16,64,64)
    const float* weights = (const float*)d_in[1];    // (64,64,16,7,7,16)
    const float* membrane = (const float*)d_in[2];   // (16,16,64,64)
    float* out = (float*)d_out;                      // [spike | mem], 2 x 1M floats

    float* sT = (float*)d_ws;                        // 1M floats = 4 MB
    float* oc = (float*)d_ws + (1 << 20);            // 1M floats = 4 MB

    k_transpose<<<4096, 256, 0, stream>>>(spikes, sT);
    k_lc<<<4096, 256, 0, stream>>>(weights, sT, oc);
    k_lif<<<256, 256, 0, stream>>>(oc, membrane, out);
}

// Round 3
// 306.046 us; speedup vs baseline: 1.1765x; 1.1765x over previous
//
#include <hip/hip_runtime.h>

// Problem constants
#define HW 64            // H = W = 64
#define KTOT 784         // 16c * 49 taps per output pixel
#define WPB_BYTES 50176u // KTOT * 16 m * 4 B of weights per (i,j)
#define W_TOTAL_BYTES (4096u * WPB_BYTES)      // 205,520,896
#define WEND (W_TOTAL_BYTES - 16u)             // last valid 16B line

// async global->LDS, 16B per lane (dest = uniform base + lane*16)
__device__ __forceinline__ void gl16(const void* g, void* l) {
    __builtin_amdgcn_global_load_lds(
        (const __attribute__((address_space(1))) unsigned int*)g,
        (__attribute__((address_space(3))) unsigned int*)l, 16, 0, 0);
}

// ---------------------------------------------------------------------------
// Kernel 1: tiled transpose spikes [b][c][h][w] -> sT [c][h][w][b]
// block = (c,h): 1024 blocks. Both global sides fully coalesced.
// ---------------------------------------------------------------------------
__global__ __launch_bounds__(256) void k_transpose(const float* __restrict__ in,
                                                   float* __restrict__ sT) {
    __shared__ float tile[16][66];
    const int c = blockIdx.x >> 6;
    const int h = blockIdx.x & 63;
    const int t = threadIdx.x;
    const int wid = t >> 6, l = t & 63;
#pragma unroll
    for (int p = 0; p < 4; ++p) {
        int b = p * 4 + wid;
        tile[b][l] = in[((b << 4) + c) * 4096 + (h << 6) + l];   // 256B rows
    }
    __syncthreads();
    const int base = ((c << 6) | h) << 10;                        // (c*64+h)*1024
#pragma unroll
    for (int p = 0; p < 4; ++p) {
        int idx = p * 256 + t;                                    // = w*16 + b
        sT[base + idx] = tile[idx & 15][idx >> 4];
    }
}

// ---------------------------------------------------------------------------
// Kernel 2: locally-connected reduce. One block per (i,j).
// Spikes: whole 784x16 patch staged to LDS once (reflection baked in).
// Weights: 7 chunks of 128k x 16m = 8KB, 3-deep global_load_lds pipeline,
// counted vmcnt(4) + raw s_barrier (never a full drain in the main loop).
// ---------------------------------------------------------------------------
__global__ __launch_bounds__(256) void k_lc(const float* __restrict__ weights,
                                            const float* __restrict__ sT,
                                            float* __restrict__ oc) {
    __shared__ __align__(16) float s_spk[12544];   // 784 k-lines * 16 b
    __shared__ __align__(16) float s_w[3][2048];   // 3 x 8KB weight chunks
    __shared__ __align__(16) float s_red[1024];    // cross-wave reduce scratch

    const int tid = threadIdx.x;
    const int bid = blockIdx.x;
    const int i = bid >> 6, j = bid & 63;
    const int wid = tid >> 6, lane = tid & 63;
    const int m = lane >> 2, bq = lane & 3;

    const char* wbase = (const char*)weights;
    const char* sbase = (const char*)sT;
    const unsigned wblk = (unsigned)bid * WPB_BYTES;

    // ---- prologue: stage all spikes (49 x 1KB instrs, split over 4 waves) ----
    for (int s = wid; s < 49; s += 4) {
        int k = s * 16 + (lane >> 2);
        int c = (k * 1338) >> 16;          // k / 49
        int xy = k - c * 49;
        int x = (xy * 37) >> 8;            // xy / 7
        int y = xy - x * 7;
        int r = i + x - 3; r = r < 0 ? -r : r; r = r > 63 ? 126 - r : r;
        int q = j + y - 3; q = q < 0 ? -q : q; q = q > 63 ? 126 - q : q;
        unsigned off = (unsigned)(((c << 12) | (r << 6) | q) << 6)
                     + (unsigned)((lane & 3) << 4);
        gl16(sbase + off, (char*)s_spk + s * 1024);
    }
    // ---- prologue: stage weight chunks 0..2 (2 instrs/thread each) ----
#pragma unroll
    for (int nn = 0; nn < 3; ++nn) {
#pragma unroll
        for (int L = 0; L < 2; ++L) {
            unsigned off = wblk + (unsigned)nn * 8192u
                         + (unsigned)((L * 4 + wid) << 10) + (unsigned)(lane << 4);
            off = off > WEND ? WEND : off;
            gl16(wbase + off, (char*)&s_w[nn][0] + ((L * 4 + wid) << 10));
        }
    }
    asm volatile("s_waitcnt vmcnt(0)" ::: "memory");
    __builtin_amdgcn_s_barrier();

    float4 acc = make_float4(0.f, 0.f, 0.f, 0.f);
    int nb = 0;                                       // n % 3
    for (int n = 0; n < 6; ++n) {
        // ---- compute chunk n from s_w[nb] (each wave: 32 k) ----
        const float* wb = &s_w[nb][0] + wid * 512 + m;
        const float4* sp = (const float4*)s_spk + (((n << 7) + (wid << 5)) << 2) + bq;
#pragma unroll
        for (int t = 0; t < 32; ++t) {
            float4 s4 = sp[t * 4];                    // ds_read_b128, broadcast
            float w = wb[t * 16];                     // ds_read_b32, broadcast
            acc.x += s4.x * w; acc.y += s4.y * w;
            acc.z += s4.z * w; acc.w += s4.w * w;
        }
        asm volatile("s_waitcnt lgkmcnt(0)" ::: "memory");
        __builtin_amdgcn_s_barrier();                 // all done reading s_w[nb]
        // ---- stage chunk n+3 into s_w[nb] (uniform 2 instrs/thread) ----
        {
            const int nc = n + 3;
#pragma unroll
            for (int L = 0; L < 2; ++L) {
                unsigned off;
                if (nc <= 6) {
                    off = wblk + (unsigned)nc * 8192u
                        + (unsigned)((L * 4 + wid) << 10) + (unsigned)(lane << 4);
                    off = off > WEND ? WEND : off;
                } else {
                    off = WEND;                        // dummy: single hot line
                }
                gl16(wbase + off, (char*)&s_w[nb][0] + ((L * 4 + wid) << 10));
            }
        }
        asm volatile("s_waitcnt vmcnt(4)" ::: "memory");  // chunk n+1 landed
        __builtin_amdgcn_s_barrier();                     // publish
        nb = nb + 1; if (nb == 3) nb = 0;
    }
    // ---- tail: chunk 6 (k 768..783) lives in s_w[0]; 4 k per wave ----
    {
        const float* wb = &s_w[0][0] + wid * 64 + m;
        const float4* sp = (const float4*)s_spk + ((768 + (wid << 2)) << 2) + bq;
#pragma unroll
        for (int t = 0; t < 4; ++t) {
            float4 s4 = sp[t * 4];
            float w = wb[t * 16];
            acc.x += s4.x * w; acc.y += s4.y * w;
            acc.z += s4.z * w; acc.w += s4.w * w;
        }
    }

    // ---- reduce the 4 wave-partials, write compact oc[ij][bm] ----
    __syncthreads();                                  // full drain OK here
    float4* scr = (float4*)s_red;
    scr[wid * 64 + lane] = acc;
    __syncthreads();
    const int b = tid >> 4, mm = tid & 15;
    const int lane_src = mm * 4 + (b >> 2);
    const int d = b & 3;
    float sum = 0.f;
#pragma unroll
    for (int p = 0; p < 4; ++p) {
        float4 v = scr[p * 64 + lane_src];
        sum += (d == 0) ? v.x : (d == 1) ? v.y : (d == 2) ? v.z : v.w;
    }
    oc[(size_t)bid * 256 + tid] = sum;
}

// ---------------------------------------------------------------------------
// Kernel 3: LDS-tiled transpose oc[ij][bm] -> out[bm][ij], fused LIF update.
// ---------------------------------------------------------------------------
__global__ __launch_bounds__(256) void k_lif(const float* __restrict__ oc,
                                             const float* __restrict__ membrane,
                                             float* __restrict__ out) {
    __shared__ float tile[64][65];
    const int tb = blockIdx.x;
    const int ij0 = (tb >> 2) * 64;
    const int bm0 = (tb & 3) * 64;
    const int t = threadIdx.x;
    const int r0 = t >> 6;
    const int cl = t & 63;

#pragma unroll
    for (int p = 0; p < 16; ++p) {
        int ijl = p * 4 + r0;
        tile[ijl][cl] = oc[(size_t)(ij0 + ijl) * 256 + bm0 + cl];
    }
    __syncthreads();
#pragma unroll
    for (int p = 0; p < 16; ++p) {
        int bml = p * 4 + r0;
        int ijl = cl;
        float local = tile[ijl][bml];
        size_t idx = (size_t)(bm0 + bml) * 4096 + (ij0 + ijl);
        float memv = membrane[idx] * 0.99f + local;
        float spk = (memv > 1.0f) ? 1.0f : 0.0f;
        float mo = (memv > 1.0f) ? 1.0f : memv;
        out[idx] = spk;
        out[idx + 1048576] = mo;
    }
}

// ---------------------------------------------------------------------------
extern "C" void kernel_launch(void* const* d_in, const int* in_sizes, int n_in,
                              void* d_out, int out_size, void* d_ws, size_t ws_size,
                              hipStream_t stream) {
    const float* spikes = (const float*)d_in[0];     // (16,16,64,64)
    const float* weights = (const float*)d_in[1];    // (64,64,16,7,7,16)
    const float* membrane = (const float*)d_in[2];   // (16,16,64,64)
    float* out = (float*)d_out;                      // [spike | mem]

    float* sT = (float*)d_ws;                        // 4 MB
    float* oc = (float*)d_ws + (1 << 20);            // 4 MB

    k_transpose<<<1024, 256, 0, stream>>>(spikes, sT);
    k_lc<<<4096, 256, 0, stream>>>(weights, sT, oc);
    k_lif<<<256, 256, 0, stream>>>(oc, membrane, out);
}

// Round 4
// 302.732 us; speedup vs baseline: 1.1894x; 1.0109x over previous
//
#include <hip/hip_runtime.h>

// Problem constants
#define HW 64            // H = W = 64
#define KTOT 784         // 16c * 49 taps per output pixel
#define WPB_BYTES 50176u // KTOT * 16 m * 4 B of weights per (i,j)
#define W_TOTAL_BYTES (4096u * WPB_BYTES)      // 205,520,896
#define WEND (W_TOTAL_BYTES - 16u)             // last valid 16B line

// async global->LDS, 16B per lane (dest = uniform base + lane*16)
__device__ __forceinline__ void gl16(const void* g, void* l) {
    __builtin_amdgcn_global_load_lds(
        (const __attribute__((address_space(1))) unsigned int*)g,
        (__attribute__((address_space(3))) unsigned int*)l, 16, 0, 0);
}

#define FMA16(acc0, acc1, acc2, acc3, wv, sv)                                 \
    acc0.x += wv.x * sv.x; acc0.y += wv.x * sv.y;                             \
    acc0.z += wv.x * sv.z; acc0.w += wv.x * sv.w;                             \
    acc1.x += wv.y * sv.x; acc1.y += wv.y * sv.y;                             \
    acc1.z += wv.y * sv.z; acc1.w += wv.y * sv.w;                             \
    acc2.x += wv.z * sv.x; acc2.y += wv.z * sv.y;                             \
    acc2.z += wv.z * sv.z; acc2.w += wv.z * sv.w;                             \
    acc3.x += wv.w * sv.x; acc3.y += wv.w * sv.y;                             \
    acc3.z += wv.w * sv.z; acc3.w += wv.w * sv.w;

// ---------------------------------------------------------------------------
// Kernel 1: tiled transpose spikes [b][c][h][w] -> sT [c][h][w][b]
// ---------------------------------------------------------------------------
__global__ __launch_bounds__(256) void k_transpose(const float* __restrict__ in,
                                                   float* __restrict__ sT) {
    __shared__ float tile[16][66];
    const int c = blockIdx.x >> 6;
    const int h = blockIdx.x & 63;
    const int t = threadIdx.x;
    const int wid = t >> 6, l = t & 63;
#pragma unroll
    for (int p = 0; p < 4; ++p) {
        int b = p * 4 + wid;
        tile[b][l] = in[((b << 4) + c) * 4096 + (h << 6) + l];
    }
    __syncthreads();
    const int base = ((c << 6) | h) << 10;
#pragma unroll
    for (int p = 0; p < 4; ++p) {
        int idx = p * 256 + t;                                    // = w*16 + b
        sT[base + idx] = tile[idx & 15][idx >> 4];
    }
}

// ---------------------------------------------------------------------------
// Kernel 2: locally-connected reduce. One block per (i,j).
// Spikes: whole 784x16 patch in LDS (reflection baked in at staging).
// Weights: 7 chunks of 128k x 16m = 8KB, 3-deep global_load_lds pipeline,
// counted vmcnt(4) + raw s_barrier.
// Lane = (kq, mq, bq); per-thread 4m x 4b accumulator:
// each inner step = 2 ds_read_b128 + 16 FMA (8x fewer LDS instrs than R3).
// ---------------------------------------------------------------------------
__global__ __launch_bounds__(256) void k_lc(const float* __restrict__ weights,
                                            const float* __restrict__ sT,
                                            float* __restrict__ oc) {
    __shared__ __align__(16) float s_spk[12544];   // 784 k-lines * 16 b (50 KB)
    __shared__ __align__(16) float s_w[3][2048];   // 3 x 8KB weight chunks

    const int tid = threadIdx.x;
    const int bid = blockIdx.x;
    const int i = bid >> 6, j = bid & 63;
    const int wid = tid >> 6, lane = tid & 63;
    const int kq = (lane >> 4) & 3;   // k sub-slot
    const int mq = (lane >> 2) & 3;   // m quad
    const int bq = lane & 3;          // b quad

    const char* wbase = (const char*)weights;
    const char* sbase = (const char*)sT;
    const unsigned wblk = (unsigned)bid * WPB_BYTES;

    // ---- prologue: stage all spikes (49 x 1KB instrs, split over 4 waves) ----
    for (int s = wid; s < 49; s += 4) {
        int k = s * 16 + (lane >> 2);
        int c = (k * 1338) >> 16;          // k / 49
        int xy = k - c * 49;
        int x = (xy * 37) >> 8;            // xy / 7
        int y = xy - x * 7;
        int r = i + x - 3; r = r < 0 ? -r : r; r = r > 63 ? 126 - r : r;
        int q = j + y - 3; q = q < 0 ? -q : q; q = q > 63 ? 126 - q : q;
        unsigned off = (unsigned)(((c << 12) | (r << 6) | q) << 6)
                     + (unsigned)((lane & 3) << 4);
        gl16(sbase + off, (char*)s_spk + s * 1024);
    }
    // ---- prologue: stage weight chunks 0..2 ----
#pragma unroll
    for (int nn = 0; nn < 3; ++nn) {
#pragma unroll
        for (int L = 0; L < 2; ++L) {
            unsigned off = wblk + (unsigned)nn * 8192u
                         + (unsigned)((L * 4 + wid) << 10) + (unsigned)(lane << 4);
            off = off > WEND ? WEND : off;
            gl16(wbase + off, (char*)&s_w[nn][0] + ((L * 4 + wid) << 10));
        }
    }
    asm volatile("s_waitcnt vmcnt(0)" ::: "memory");
    __builtin_amdgcn_s_barrier();

    float4 acc0 = make_float4(0.f, 0.f, 0.f, 0.f);
    float4 acc1 = make_float4(0.f, 0.f, 0.f, 0.f);
    float4 acc2 = make_float4(0.f, 0.f, 0.f, 0.f);
    float4 acc3 = make_float4(0.f, 0.f, 0.f, 0.f);

    const int klb = wid * 32 + kq;                    // local k base (step 4)
    int nb = 0;                                       // n % 3
    for (int n = 0; n < 6; ++n) {
        // ---- compute chunk n: per lane 8 iters x (2 ds_read_b128 + 16 FMA) ----
        const float4* sp = (const float4*)s_spk + (((n << 7) + klb) << 2) + bq;
        const float4* wp = (const float4*)&s_w[nb][0] + (klb << 2) + mq;
#pragma unroll
        for (int t = 0; t < 8; ++t) {
            float4 sv = sp[t * 16];                   // 4 spikes (b), broadcast x4
            float4 wv = wp[t * 16];                   // 4 weights (m), broadcast x4
            FMA16(acc0, acc1, acc2, acc3, wv, sv)
        }
        asm volatile("s_waitcnt lgkmcnt(0)" ::: "memory");
        __builtin_amdgcn_s_barrier();                 // all done reading s_w[nb]
        // ---- stage chunk n+3 into s_w[nb] (uniform 2 instrs/thread) ----
        {
            const int nc = n + 3;
#pragma unroll
            for (int L = 0; L < 2; ++L) {
                unsigned off;
                if (nc <= 6) {
                    off = wblk + (unsigned)nc * 8192u
                        + (unsigned)((L * 4 + wid) << 10) + (unsigned)(lane << 4);
                    off = off > WEND ? WEND : off;
                } else {
                    off = WEND;                        // dummy: single hot line
                }
                gl16(wbase + off, (char*)&s_w[nb][0] + ((L * 4 + wid) << 10));
            }
        }
        asm volatile("s_waitcnt vmcnt(4)" ::: "memory");  // chunk n+1 landed
        __builtin_amdgcn_s_barrier();                     // publish
        nb = nb + 1; if (nb == 3) nb = 0;
    }
    // ---- tail: chunk 6 (k 768..783) in s_w[0]; 1 iter per lane ----
    {
        const int klt = wid * 4 + kq;
        float4 sv = *((const float4*)s_spk + ((768 + klt) << 2) + bq);
        float4 wv = *((const float4*)&s_w[0][0] + (klt << 2) + mq);
        FMA16(acc0, acc1, acc2, acc3, wv, sv)
    }

    // ---- reduce 16 partials (4 waves x 4 kq) via LDS scratch (alias s_spk) ----
    __syncthreads();                                  // done with s_spk contents
    float* scr = s_spk;                               // scr[g][m][b], g = wid*4+kq
    {
        const int g = wid * 4 + kq;
        float4* scw = (float4*)scr;
        scw[(g * 16 + mq * 4 + 0) * 4 + bq] = acc0;
        scw[(g * 16 + mq * 4 + 1) * 4 + bq] = acc1;
        scw[(g * 16 + mq * 4 + 2) * 4 + bq] = acc2;
        scw[(g * 16 + mq * 4 + 3) * 4 + bq] = acc3;
    }
    __syncthreads();
    const int b = tid >> 4, mm = tid & 15;
    float sum = 0.f;
#pragma unroll
    for (int g = 0; g < 16; ++g) {
        sum += scr[g * 256 + mm * 16 + b];
    }
    oc[(size_t)bid * 256 + tid] = sum;                // oc[ij][b*16+m], coalesced
}

// ---------------------------------------------------------------------------
// Kernel 3: LDS-tiled transpose oc[ij][bm] -> out[bm][ij], fused LIF update.
// ---------------------------------------------------------------------------
__global__ __launch_bounds__(256) void k_lif(const float* __restrict__ oc,
                                             const float* __restrict__ membrane,
                                             float* __restrict__ out) {
    __shared__ float tile[64][65];
    const int tb = blockIdx.x;
    const int ij0 = (tb >> 2) * 64;
    const int bm0 = (tb & 3) * 64;
    const int t = threadIdx.x;
    const int r0 = t >> 6;
    const int cl = t & 63;

#pragma unroll
    for (int p = 0; p < 16; ++p) {
        int ijl = p * 4 + r0;
        tile[ijl][cl] = oc[(size_t)(ij0 + ijl) * 256 + bm0 + cl];
    }
    __syncthreads();
#pragma unroll
    for (int p = 0; p < 16; ++p) {
        int bml = p * 4 + r0;
        int ijl = cl;
        float local = tile[ijl][bml];
        size_t idx = (size_t)(bm0 + bml) * 4096 + (ij0 + ijl);
        float memv = membrane[idx] * 0.99f + local;
        float spk = (memv > 1.0f) ? 1.0f : 0.0f;
        float mo = (memv > 1.0f) ? 1.0f : memv;
        out[idx] = spk;
        out[idx + 1048576] = mo;
    }
}

// ---------------------------------------------------------------------------
extern "C" void kernel_launch(void* const* d_in, const int* in_sizes, int n_in,
                              void* d_out, int out_size, void* d_ws, size_t ws_size,
                              hipStream_t stream) {
    const float* spikes = (const float*)d_in[0];     // (16,16,64,64)
    const float* weights = (const float*)d_in[1];    // (64,64,16,7,7,16)
    const float* membrane = (const float*)d_in[2];   // (16,16,64,64)
    float* out = (float*)d_out;                      // [spike | mem]

    float* sT = (float*)d_ws;                        // 4 MB
    float* oc = (float*)d_ws + (1 << 20);            // 4 MB

    k_transpose<<<1024, 256, 0, stream>>>(spikes, sT);
    k_lc<<<4096, 256, 0, stream>>>(weights, sT, oc);
    k_lif<<<256, 256, 0, stream>>>(oc, membrane, out);
}

// Round 7
// 301.356 us; speedup vs baseline: 1.1948x; 1.0046x over previous
//
#include <hip/hip_runtime.h>

// Problem constants
#define KTOT 784         // 16c * 49 taps per output pixel
#define WPB 12544        // KTOT * 16 m floats of weights per (i,j)

// async global->LDS, 16B per lane (dest = uniform base + lane*16)
__device__ __forceinline__ void gl16(const void* g, void* l) {
    __builtin_amdgcn_global_load_lds(
        (const __attribute__((address_space(1))) unsigned int*)g,
        (__attribute__((address_space(3))) unsigned int*)l, 16, 0, 0);
}

#define FMA16(acc0, acc1, acc2, acc3, wv, sv)                                 \
    acc0.x += wv.x * sv.x; acc0.y += wv.x * sv.y;                             \
    acc0.z += wv.x * sv.z; acc0.w += wv.x * sv.w;                             \
    acc1.x += wv.y * sv.x; acc1.y += wv.y * sv.y;                             \
    acc1.z += wv.y * sv.z; acc1.w += wv.y * sv.w;                             \
    acc2.x += wv.z * sv.x; acc2.y += wv.z * sv.y;                             \
    acc2.z += wv.z * sv.z; acc2.w += wv.z * sv.w;                             \
    acc3.x += wv.w * sv.x; acc3.y += wv.w * sv.y;                             \
    acc3.z += wv.w * sv.z; acc3.w += wv.w * sv.w;

// ---------------------------------------------------------------------------
// Kernel 1: tiled transpose spikes [b][c][h][w] -> sT [c][h][w][b]
// ---------------------------------------------------------------------------
__global__ __launch_bounds__(256) void k_transpose(const float* __restrict__ in,
                                                   float* __restrict__ sT) {
    __shared__ float tile[16][66];
    const int c = blockIdx.x >> 6;
    const int h = blockIdx.x & 63;
    const int t = threadIdx.x;
    const int wid = t >> 6, l = t & 63;
#pragma unroll
    for (int p = 0; p < 4; ++p) {
        int b = p * 4 + wid;
        tile[b][l] = in[((b << 4) + c) * 4096 + (h << 6) + l];
    }
    __syncthreads();
    const int base = ((c << 6) | h) << 10;
#pragma unroll
    for (int p = 0; p < 4; ++p) {
        int idx = p * 256 + t;                                    // = w*16 + b
        sT[base + idx] = tile[idx & 15][idx >> 4];
    }
}

// ---------------------------------------------------------------------------
// Kernel 2: locally-connected reduce. One block per (i,j).
// Spikes: whole 784x16 patch in LDS (reflection baked in at staging), 50 KB
//         -> 3 blocks / 12 waves per CU.
// Weights: plain global_load_dwordx4 straight to registers — per wave-instr
//          the 64 lanes cover 4 consecutive klines x 4 mq (bq lanes are
//          same-address, coalescer dedups) = 256 contiguous bytes, each
//          weight line fetched from L2/HBM exactly once per block.
// NO barriers / vmcnt choreography in the main loop: waves run free, 12/CU.
// ---------------------------------------------------------------------------
__global__ __launch_bounds__(256) void k_lc(const float* __restrict__ weights,
                                            const float* __restrict__ sT,
                                            float* __restrict__ oc) {
    __shared__ __align__(16) float s_spk[12544];   // 784 k-lines * 16 b (50 KB)

    const int tid = threadIdx.x;
    const int bid = blockIdx.x;
    const int i = bid >> 6, j = bid & 63;
    const int wid = tid >> 6, lane = tid & 63;
    const int kq = (lane >> 4) & 3;   // k sub-slot
    const int mq = (lane >> 2) & 3;   // m quad
    const int bq = lane & 3;          // b quad

    // ---- prologue: stage all spikes (49 x 1KB instrs, split over 4 waves) ----
    const char* sbase = (const char*)sT;
    for (int s = wid; s < 49; s += 4) {
        int k = s * 16 + (lane >> 2);
        int c = (k * 1338) >> 16;          // k / 49
        int xy = k - c * 49;
        int x = (xy * 37) >> 8;            // xy / 7
        int y = xy - x * 7;
        int r = i + x - 3; r = r < 0 ? -r : r; r = r > 63 ? 126 - r : r;
        int q = j + y - 3; q = q < 0 ? -q : q; q = q > 63 ? 126 - q : q;
        unsigned off = (unsigned)(((c << 12) | (r << 6) | q) << 6)
                     + (unsigned)((lane & 3) << 4);
        gl16(sbase + off, (char*)s_spk + s * 1024);
    }
    asm volatile("s_waitcnt vmcnt(0)" ::: "memory");
    __syncthreads();

    float4 acc0 = make_float4(0.f, 0.f, 0.f, 0.f);
    float4 acc1 = make_float4(0.f, 0.f, 0.f, 0.f);
    float4 acc2 = make_float4(0.f, 0.f, 0.f, 0.f);
    float4 acc3 = make_float4(0.f, 0.f, 0.f, 0.f);

    // this thread's kline base: klines kbase + 4t, t = 0..48 (wid partitions k)
    const int kbase = wid * 196 + kq;
    const float4* sp = (const float4*)s_spk + kbase * 4 + bq;
    const float4* wp = (const float4*)(weights + (size_t)bid * WPB) + kbase * 4 + mq;

#pragma unroll 7
    for (int t = 0; t < 49; ++t) {
        float4 sv = sp[t * 16];            // ds_read_b128, 4-way broadcast
        float4 wv = wp[t * 16];            // global_load_dwordx4, L2-dedup'd
        FMA16(acc0, acc1, acc2, acc3, wv, sv)
    }

    // ---- reduce 16 partials (4 waves x 4 kq) via LDS scratch (alias s_spk) ----
    __syncthreads();                                  // done with s_spk contents
    float* scr = s_spk;                               // scr[g][m][b], g = wid*4+kq
    {
        const int g = wid * 4 + kq;
        float4* scw = (float4*)scr;
        scw[(g * 16 + mq * 4 + 0) * 4 + bq] = acc0;
        scw[(g * 16 + mq * 4 + 1) * 4 + bq] = acc1;
        scw[(g * 16 + mq * 4 + 2) * 4 + bq] = acc2;
        scw[(g * 16 + mq * 4 + 3) * 4 + bq] = acc3;
    }
    __syncthreads();
    const int b = tid >> 4, mm = tid & 15;
    float sum = 0.f;
#pragma unroll
    for (int g = 0; g < 16; ++g) {
        sum += scr[g * 256 + mm * 16 + b];
    }
    oc[(size_t)bid * 256 + tid] = sum;                // oc[ij][b*16+m], coalesced
}

// ---------------------------------------------------------------------------
// Kernel 3: LDS-tiled transpose oc[ij][bm] -> out[bm][ij], fused LIF update.
// ---------------------------------------------------------------------------
__global__ __launch_bounds__(256) void k_lif(const float* __restrict__ oc,
                                             const float* __restrict__ membrane,
                                             float* __restrict__ out) {
    __shared__ float tile[64][65];
    const int tb = blockIdx.x;
    const int ij0 = (tb >> 2) * 64;
    const int bm0 = (tb & 3) * 64;
    const int t = threadIdx.x;
    const int r0 = t >> 6;
    const int cl = t & 63;

#pragma unroll
    for (int p = 0; p < 16; ++p) {
        int ijl = p * 4 + r0;
        tile[ijl][cl] = oc[(size_t)(ij0 + ijl) * 256 + bm0 + cl];
    }
    __syncthreads();
#pragma unroll
    for (int p = 0; p < 16; ++p) {
        int bml = p * 4 + r0;
        int ijl = cl;
        float local = tile[ijl][bml];
        size_t idx = (size_t)(bm0 + bml) * 4096 + (ij0 + ijl);
        float memv = membrane[idx] * 0.99f + local;
        float spk = (memv > 1.0f) ? 1.0f : 0.0f;
        float mo = (memv > 1.0f) ? 1.0f : memv;
        out[idx] = spk;
        out[idx + 1048576] = mo;
    }
}

// ---------------------------------------------------------------------------
extern "C" void kernel_launch(void* const* d_in, const int* in_sizes, int n_in,
                              void* d_out, int out_size, void* d_ws, size_t ws_size,
                              hipStream_t stream) {
    const float* spikes = (const float*)d_in[0];     // (16,16,64,64)
    const float* weights = (const float*)d_in[1];    // (64,64,16,7,7,16)
    const float* membrane = (const float*)d_in[2];   // (16,16,64,64)
    float* out = (float*)d_out;                      // [spike | mem]

    float* sT = (float*)d_ws;                        // 4 MB
    float* oc = (float*)d_ws + (1 << 20);            // 4 MB

    k_transpose<<<1024, 256, 0, stream>>>(spikes, sT);
    k_lc<<<4096, 256, 0, stream>>>(weights, sT, oc);
    k_lif<<<256, 256, 0, stream>>>(oc, membrane, out);
}